// Round 1
// baseline (490.144 us; speedup 1.0000x reference)
//
#include <hip/hip_runtime.h>
#include <hip/hip_bf16.h>

using bf16x8 = __attribute__((ext_vector_type(8))) short;
using f32x4  = __attribute__((ext_vector_type(4))) float;

constexpr int BATCH = 32, CIN = 64, H = 128, W = 128, COUT = 128, OH = 126, OW = 126;
constexpr int OHT = 2, OWT = 64, IHT = OHT + 2, IWT = OWT + 2;   // 4, 66
constexpr int XUNITS = IHT * IWT * CIN / 8;                      // 2112 16B-units
constexpr int AROW_U = 9;                                        // padded A row = 9 units (72 bf16)
constexpr int NTHREADS = 512;

// ---- weight transform: fp32 OIHW -> bf16 [kh*3+kw][cout][cin] in workspace
__global__ void wt_transform(const float* __restrict__ w, ushort* __restrict__ wt) {
    int t = blockIdx.x * 256 + threadIdx.x;
    if (t >= 9 * COUT * CIN) return;
    int kk  = t / (COUT * CIN);
    int rem = t - kk * (COUT * CIN);
    int co = rem >> 6, ci = rem & 63;
    float v = w[(size_t)(co * CIN + ci) * 9 + kk];
    __hip_bfloat16 h = __float2bfloat16(v);
    wt[t] = *reinterpret_cast<ushort*>(&h);
}

__global__ __launch_bounds__(NTHREADS, 4) void conv_mfma(
    const float* __restrict__ x, const ushort* __restrict__ wt,
    const float* __restrict__ bias, const float* __restrict__ mult,
    float* __restrict__ out)
{
    __shared__ __align__(16) ushort xs[XUNITS * 8];      // 33792 B, swizzled channel-last x tile
    __shared__ __align__(16) ushort as[COUT * AROW_U * 8]; // 18432 B, padded A slice

    const int tid = threadIdx.x;
    const int b   = blockIdx.z;
    const int oh0 = blockIdx.y * OHT;
    const int ow0 = blockIdx.x * OWT;

    // ---- stage x tile: fp32 NCHW -> bf16 [ih][iw][cin], 16B-unit XOR swizzle (c8 ^ (iw&7))
    for (int j = tid; j < XUNITS; j += NTHREADS) {
        int c8  = j / (IHT * IWT);
        int rem = j - c8 * (IHT * IWT);
        int ih  = rem / IWT;
        int iw  = rem - ih * IWT;
        int ihg = oh0 + ih;                       // <= 127 always (oh0 <= 124)
        int iwg = ow0 + iw; iwg = iwg > W - 1 ? W - 1 : iwg;  // clamp; garbage cols masked at store
        const float* xp = x + (size_t)(b * CIN + c8 * 8) * (H * W) + ihg * W + iwg;
        bf16x8 v;
        #pragma unroll
        for (int i = 0; i < 8; ++i) {
            __hip_bfloat16 h = __float2bfloat16(xp[(size_t)i * H * W]);
            v[i] = (short)*reinterpret_cast<ushort*>(&h);
        }
        int u = (ih * IWT + iw) * 8 + (c8 ^ (iw & 7));
        *reinterpret_cast<bf16x8*>(&xs[u * 8]) = v;
    }

    const int wave = tid >> 6, lane = tid & 63;
    const int l15 = lane & 15, l4 = lane >> 4;
    const int wm = wave >> 2;          // cout half (64 couts)
    const int wr = (wave >> 1) & 1;    // output row within tile
    const int wc = wave & 1;           // 32-px column half

    f32x4 acc[4][2];
    #pragma unroll
    for (int m = 0; m < 4; ++m)
        #pragma unroll
        for (int t = 0; t < 2; ++t)
            acc[m][t] = (f32x4){0.f, 0.f, 0.f, 0.f};

    for (int kk = 0; kk < 9; ++kk) {
        __syncthreads();               // covers x-stage (kk==0) and prior reads of as
        // ---- stage A slice [128 cout][64 cin] bf16, rows padded to 9 units
        const ushort* wsl = wt + kk * (COUT * CIN);
        for (int j = tid; j < COUT * CIN / 8; j += NTHREADS) {
            int co = j >> 3, c = j & 7;
            bf16x8 v = *reinterpret_cast<const bf16x8*>(wsl + j * 8);
            *reinterpret_cast<bf16x8*>(&as[(co * AROW_U + c) * 8]) = v;
        }
        __syncthreads();

        const int kh = kk / 3, kw = kk - kh * 3;
        #pragma unroll
        for (int hf = 0; hf < 2; ++hf) {     // two 32-cin K-steps
            bf16x8 af[4], bfr[2];
            #pragma unroll
            for (int m = 0; m < 4; ++m) {
                int co = wm * 64 + m * 16 + l15;
                af[m] = *reinterpret_cast<const bf16x8*>(&as[(co * AROW_U + hf * 4 + l4) * 8]);
            }
            #pragma unroll
            for (int t = 0; t < 2; ++t) {
                int iwr = wc * 32 + t * 16 + l15 + kw;
                int ihr = wr + kh;
                int u = (ihr * IWT + iwr) * 8 + ((hf * 4 + l4) ^ (iwr & 7));
                bfr[t] = *reinterpret_cast<const bf16x8*>(&xs[u * 8]);
            }
            #pragma unroll
            for (int m = 0; m < 4; ++m)
                #pragma unroll
                for (int t = 0; t < 2; ++t)
                    acc[m][t] = __builtin_amdgcn_mfma_f32_16x16x32_bf16(af[m], bfr[t], acc[m][t], 0, 0, 0);
        }
    }

    // ---- epilogue: bias -> mult -> leaky relu -> gelu(tanh), masked store
    const int oh = oh0 + wr;
    #pragma unroll
    for (int m = 0; m < 4; ++m) {
        #pragma unroll
        for (int i = 0; i < 4; ++i) {
            int co = wm * 64 + m * 16 + l4 * 4 + i;   // C/D: row=(lane>>4)*4+i, col=lane&15
            float bi = bias[co];
            float mu = mult[co];
            #pragma unroll
            for (int t = 0; t < 2; ++t) {
                int ow = ow0 + wc * 32 + t * 16 + l15;
                if (ow < OW) {
                    float y = acc[m][t][i] + bi;
                    y *= mu;
                    y = y >= 0.f ? y : 0.01f * y;
                    float z = 0.7978845608028654f * (y + 0.044715f * y * y * y);
                    float e = __expf(2.0f * z);
                    float th = 1.0f - 2.0f / (e + 1.0f);   // tanh(z), saturates cleanly
                    out[((size_t)(b * COUT + co) * OH + oh) * OW + ow] = 0.5f * y * (1.0f + th);
                }
            }
        }
    }
}

extern "C" void kernel_launch(void* const* d_in, const int* in_sizes, int n_in,
                              void* d_out, int out_size, void* d_ws, size_t ws_size,
                              hipStream_t stream)
{
    const float* x    = (const float*)d_in[0];
    const float* w    = (const float*)d_in[1];
    const float* bias = (const float*)d_in[2];
    const float* mult = (const float*)d_in[3];
    float* out = (float*)d_out;
    ushort* wt = (ushort*)d_ws;   // needs 9*128*64*2 = 147456 B

    hipLaunchKernelGGL(wt_transform, dim3((9 * COUT * CIN + 255) / 256), dim3(256), 0, stream, w, wt);
    dim3 grid((OW + OWT - 1) / OWT, OH / OHT, BATCH);   // (2, 63, 32)
    hipLaunchKernelGGL(conv_mfma, grid, dim3(NTHREADS), 0, stream, x, wt, bias, mult, out);
}

// Round 2
// 453.215 us; speedup vs baseline: 1.0815x; 1.0815x over previous
//
#include <hip/hip_runtime.h>
#include <hip/hip_bf16.h>

using bf16x8 = __attribute__((ext_vector_type(8))) short;
using f32x16 = __attribute__((ext_vector_type(16))) float;

constexpr int BATCH = 32, CIN = 64, H = 128, W = 128, COUT = 128, OH = 126, OW = 126;
constexpr int OHT = 2, OWT = 64, IHT = OHT + 2, IWT = OWT + 2;   // 4, 66
constexpr int XUNITS = IHT * IWT * (CIN / 8);                    // 2112 16B-units
constexpr int NTH = 512;
constexpr int NFRAG = 9 * 4 * 4 * 64;                            // kk*kq*m*lane

// ---- weight transform: fp32 OIHW -> bf16 MFMA-A fragments [kk][kq][m][lane][8]
// A-frag (32x32x16): row(cout within m-group) = lane&31, k = (lane>>5)*8 + j
__global__ void wt_transform(const float* __restrict__ w, ushort* __restrict__ wtf) {
    int t = blockIdx.x * 256 + threadIdx.x;
    if (t >= NFRAG * 8) return;
    int j  = t & 7;
    int l  = (t >> 3) & 63;
    int m  = (t >> 9) & 3;
    int kq = (t >> 11) & 3;
    int kk = t >> 13;
    int co = m * 32 + (l & 31);
    int ci = kq * 16 + (l >> 5) * 8 + j;
    float v = w[(size_t)(co * CIN + ci) * 9 + kk];
    __hip_bfloat16 h = __float2bfloat16(v);
    wtf[t] = *reinterpret_cast<ushort*>(&h);
}

__global__ __launch_bounds__(NTH, 4) void conv_mfma(
    const float* __restrict__ x, const ushort* __restrict__ wtf,
    const float* __restrict__ bias, const float* __restrict__ mult,
    float* __restrict__ out)
{
    __shared__ __align__(16) ushort xs[XUNITS * 8];   // 33792 B

    const int tid  = threadIdx.x;
    const int b    = blockIdx.z;
    const int oh0  = blockIdx.y * OHT;
    const int ow0  = blockIdx.x * OWT;
    const int wave = tid >> 6, lane = tid & 63;
    const int m    = wave >> 1;        // cout group (32 couts)
    const int r    = wave & 1;         // oh row within tile
    const int l31  = lane & 31, l5 = lane >> 5;

    const bf16x8* wf = reinterpret_cast<const bf16x8*>(wtf);

    // ---- prefetch A fragments for kk=0 (4 coalesced 1KB wave loads)
    bf16x8 aC[4], aN[4];
    #pragma unroll
    for (int kq = 0; kq < 4; ++kq)
        aC[kq] = wf[((0 * 4 + kq) * 4 + m) * 64 + lane];

    // ---- stage x tile: fp32 NCHW -> bf16 [ih][iw][cin], 16B-unit XOR swizzle
    for (int j = tid; j < XUNITS; j += NTH) {
        int c8  = j / (IHT * IWT);
        int rem = j - c8 * (IHT * IWT);
        int ih  = rem / IWT;
        int iw  = rem - ih * IWT;
        int ihg = oh0 + ih;                               // always < H
        int iwg = ow0 + iw; iwg = iwg > W - 1 ? W - 1 : iwg;
        const float* xp = x + (size_t)(b * CIN + c8 * 8) * (H * W) + ihg * W + iwg;
        bf16x8 v;
        #pragma unroll
        for (int i = 0; i < 8; ++i) {
            __hip_bfloat16 h = __float2bfloat16(xp[(size_t)i * H * W]);
            v[i] = (short)*reinterpret_cast<ushort*>(&h);
        }
        int u = (ih * IWT + iw) * 8 + (c8 ^ (iw & 7));
        *reinterpret_cast<bf16x8*>(&xs[u * 8]) = v;
    }
    __syncthreads();                                      // the ONLY barrier

    f32x16 acc0, acc1;
    #pragma unroll
    for (int i = 0; i < 16; ++i) { acc0[i] = 0.f; acc1[i] = 0.f; }

    #pragma unroll 1
    for (int kk = 0; kk < 9; ++kk) {
        // prefetch next kk's A fragments (redundant reload at kk=8, harmless)
        int kn = kk < 8 ? kk + 1 : 8;
        #pragma unroll
        for (int kq = 0; kq < 4; ++kq)
            aN[kq] = wf[((kn * 4 + kq) * 4 + m) * 64 + lane];

        const int kh = kk / 3, kw = kk - kh * 3;
        const int q  = l31 + kw;                 // tile-local input col for t=0
        const int s  = q & 7;
        const int base = ((r + kh) * IWT + q) * 8;

        #pragma unroll
        for (int kq = 0; kq < 4; ++kq) {
            const int cu = (kq * 2 + l5) ^ s;
            bf16x8 b0 = *reinterpret_cast<const bf16x8*>(&xs[(base + cu) * 8]);
            bf16x8 b1 = *reinterpret_cast<const bf16x8*>(&xs[(base + 256 + cu) * 8]);
            acc0 = __builtin_amdgcn_mfma_f32_32x32x16_bf16(aC[kq], b0, acc0, 0, 0, 0);
            acc1 = __builtin_amdgcn_mfma_f32_32x32x16_bf16(aC[kq], b1, acc1, 0, 0, 0);
        }
        #pragma unroll
        for (int kq = 0; kq < 4; ++kq) aC[kq] = aN[kq];
    }

    // ---- epilogue: bias -> mult -> leaky relu -> gelu(tanh)
    const int oh = oh0 + r;
    const int ow_t0 = ow0 + l31;            // always < OW (<= 95)
    const int ow_t1 = ow0 + 32 + l31;
    const bool m1 = ow_t1 < OW;
    #pragma unroll
    for (int i = 0; i < 16; ++i) {
        const int co = m * 32 + (i & 3) + 8 * (i >> 2) + 4 * l5;  // C/D row map
        const float bi = bias[co];
        const float mu = mult[co];
        float* p = out + ((size_t)(b * COUT + co) * OH + oh) * OW;
        {
            float y = acc0[i] + bi;
            y *= mu;
            y = y >= 0.f ? y : 0.01f * y;
            float z = 0.7978845608028654f * (y + 0.044715f * y * y * y);
            float e = __expf(2.0f * z);
            p[ow_t0] = 0.5f * y * (1.0f + (1.0f - 2.0f / (e + 1.0f)));
        }
        if (m1) {
            float y = acc1[i] + bi;
            y *= mu;
            y = y >= 0.f ? y : 0.01f * y;
            float z = 0.7978845608028654f * (y + 0.044715f * y * y * y);
            float e = __expf(2.0f * z);
            p[ow_t1] = 0.5f * y * (1.0f + (1.0f - 2.0f / (e + 1.0f)));
        }
    }
}

extern "C" void kernel_launch(void* const* d_in, const int* in_sizes, int n_in,
                              void* d_out, int out_size, void* d_ws, size_t ws_size,
                              hipStream_t stream)
{
    const float* x    = (const float*)d_in[0];
    const float* w    = (const float*)d_in[1];
    const float* bias = (const float*)d_in[2];
    const float* mult = (const float*)d_in[3];
    float* out = (float*)d_out;
    ushort* wtf = (ushort*)d_ws;   // 9*4*4*64*8*2 = 147456 B

    hipLaunchKernelGGL(wt_transform, dim3((NFRAG * 8 + 255) / 256), dim3(256), 0, stream, w, wtf);
    dim3 grid(OW / OWT + (OW % OWT ? 1 : 0), OH / OHT, BATCH);   // (2, 63, 32)
    hipLaunchKernelGGL(conv_mfma, grid, dim3(NTH), 0, stream, x, wtf, bias, mult, out);
}

// Round 3
// 436.886 us; speedup vs baseline: 1.1219x; 1.0374x over previous
//
#include <hip/hip_runtime.h>
#include <hip/hip_bf16.h>

using bf16x8 = __attribute__((ext_vector_type(8))) short;
using f32x16 = __attribute__((ext_vector_type(16))) float;

constexpr int BATCH = 32, CIN = 64, H = 128, W = 128, COUT = 128, OH = 126, OW = 126;
constexpr int OHT = 4, OWT = 64, IHT = OHT + 2, IWT = OWT + 2;   // 6, 66
constexpr int NPIX = IHT * IWT;                                  // 396 pixels
constexpr int XUNITS = NPIX * (CIN / 8);                         // 3168 16B-units (50688 B)
constexpr int NTH = 1024;
constexpr int NFRAG = 9 * 4 * 4 * 64;                            // kk*kq*m*lane

// ---- weight transform: fp32 OIHW -> bf16 MFMA-A fragments [kk][kq][m][lane][8]
// A-frag (32x32x16): row(cout within m-group) = lane&31, k = (lane>>5)*8 + j
__global__ void wt_transform(const float* __restrict__ w, ushort* __restrict__ wtf) {
    int t = blockIdx.x * 256 + threadIdx.x;
    if (t >= NFRAG * 8) return;
    int j  = t & 7;
    int l  = (t >> 3) & 63;
    int m  = (t >> 9) & 3;
    int kq = (t >> 11) & 3;
    int kk = t >> 13;
    int co = m * 32 + (l & 31);
    int ci = kq * 16 + (l >> 5) * 8 + j;
    float v = w[(size_t)(co * CIN + ci) * 9 + kk];
    __hip_bfloat16 h = __float2bfloat16(v);
    wtf[t] = *reinterpret_cast<ushort*>(&h);
}

__global__ __launch_bounds__(NTH, 8) void conv_mfma(
    const float* __restrict__ x, const ushort* __restrict__ wtf,
    const float* __restrict__ bias, const float* __restrict__ mult,
    float* __restrict__ out)
{
    __shared__ __align__(16) ushort xs[XUNITS * 8];   // 50688 B

    const int tid  = threadIdx.x;
    const int b    = blockIdx.z;
    const int oh0  = blockIdx.y * OHT;
    const int ow0  = blockIdx.x * OWT;
    const int wave = tid >> 6, lane = tid & 63;
    const int m    = wave >> 2;        // cout group (32 couts)
    const int r    = wave & 3;         // oh row within tile
    const int l31  = lane & 31, l5 = lane >> 5;

    const bf16x8* wf = reinterpret_cast<const bf16x8*>(wtf);

    // ---- prefetch A fragments for kk=0 (4 coalesced 1KB wave loads)
    bf16x8 aC[4], aN[4];
    #pragma unroll
    for (int kq = 0; kq < 4; ++kq)
        aC[kq] = wf[((0 * 4 + kq) * 4 + m) * 64 + lane];

    // ---- stage x tile: fp32 NCHW -> bf16 [pix][cin], unit = p*8 + (c8 ^ (p&7))
    // consecutive lanes -> consecutive p at fixed c8 -> xor cycles all 8 bank
    // groups -> conflict-free ds_write_b128; global loads stay coalesced.
    for (int j = tid; j < XUNITS; j += NTH) {
        int c8 = j / NPIX;
        int p  = j - c8 * NPIX;
        int ih = p / IWT;
        int iw = p - ih * IWT;
        int ihg = oh0 + ih; ihg = ihg > H - 1 ? H - 1 : ihg;   // tail clamp
        int iwg = ow0 + iw; iwg = iwg > W - 1 ? W - 1 : iwg;   // halo clamp
        const float* xp = x + (size_t)(b * CIN + c8 * 8) * (H * W) + ihg * W + iwg;
        bf16x8 v;
        #pragma unroll
        for (int i = 0; i < 8; ++i) {
            __hip_bfloat16 h = __float2bfloat16(xp[(size_t)i * H * W]);
            v[i] = (short)*reinterpret_cast<ushort*>(&h);
        }
        int u = p * 8 + (c8 ^ (p & 7));
        *reinterpret_cast<bf16x8*>(&xs[u * 8]) = v;
    }
    __syncthreads();                                      // the ONLY barrier

    f32x16 acc0, acc1;
    #pragma unroll
    for (int i = 0; i < 16; ++i) { acc0[i] = 0.f; acc1[i] = 0.f; }

    #pragma unroll 1
    for (int kk = 0; kk < 9; ++kk) {
        // prefetch next kk's A fragments (redundant reload at kk=8, harmless)
        int kn = kk < 8 ? kk + 1 : 8;
        #pragma unroll
        for (int kq = 0; kq < 4; ++kq)
            aN[kq] = wf[((kn * 4 + kq) * 4 + m) * 64 + lane];

        const int kh = kk / 3, kw = kk - kh * 3;
        const int p0 = (r + kh) * IWT + l31 + kw;    // t=0 pixel; (p0+32)&7 == p0&7
        const int s  = p0 & 7;
        const int ub = p0 * 8;

        #pragma unroll
        for (int kq = 0; kq < 4; ++kq) {
            const int cu = (kq * 2 + l5) ^ s;
            bf16x8 b0 = *reinterpret_cast<const bf16x8*>(&xs[(ub + cu) * 8]);
            bf16x8 b1 = *reinterpret_cast<const bf16x8*>(&xs[(ub + 256 + cu) * 8]);
            acc0 = __builtin_amdgcn_mfma_f32_32x32x16_bf16(aC[kq], b0, acc0, 0, 0, 0);
            acc1 = __builtin_amdgcn_mfma_f32_32x32x16_bf16(aC[kq], b1, acc1, 0, 0, 0);
        }
        #pragma unroll
        for (int kq = 0; kq < 4; ++kq) aC[kq] = aN[kq];
    }

    // ---- epilogue: bias -> mult -> leaky relu -> gelu(tanh)
    const int oh = oh0 + r;
    if (oh < OH) {
        const int ow_t0 = ow0 + l31;            // always < OW (<= 95)
        const int ow_t1 = ow0 + 32 + l31;
        const bool m1 = ow_t1 < OW;
        #pragma unroll
        for (int i = 0; i < 16; ++i) {
            const int co = m * 32 + (i & 3) + 8 * (i >> 2) + 4 * l5;  // C/D row map
            const float bi = bias[co];
            const float mu = mult[co];
            float* p = out + ((size_t)(b * COUT + co) * OH + oh) * OW;
            {
                float y = acc0[i] + bi;
                y *= mu;
                y = y >= 0.f ? y : 0.01f * y;
                float z = 0.7978845608028654f * (y + 0.044715f * y * y * y);
                float e = __expf(2.0f * z);
                p[ow_t0] = 0.5f * y * (1.0f + (1.0f - 2.0f / (e + 1.0f)));
            }
            if (m1) {
                float y = acc1[i] + bi;
                y *= mu;
                y = y >= 0.f ? y : 0.01f * y;
                float z = 0.7978845608028654f * (y + 0.044715f * y * y * y);
                float e = __expf(2.0f * z);
                p[ow_t1] = 0.5f * y * (1.0f + (1.0f - 2.0f / (e + 1.0f)));
            }
        }
    }
}

extern "C" void kernel_launch(void* const* d_in, const int* in_sizes, int n_in,
                              void* d_out, int out_size, void* d_ws, size_t ws_size,
                              hipStream_t stream)
{
    const float* x    = (const float*)d_in[0];
    const float* w    = (const float*)d_in[1];
    const float* bias = (const float*)d_in[2];
    const float* mult = (const float*)d_in[3];
    float* out = (float*)d_out;
    ushort* wtf = (ushort*)d_ws;   // 9*4*4*64*8*2 = 147456 B

    hipLaunchKernelGGL(wt_transform, dim3((NFRAG * 8 + 255) / 256), dim3(256), 0, stream, w, wtf);
    dim3 grid(2, (OH + OHT - 1) / OHT, BATCH);   // (2, 32, 32) = 2048 blocks
    hipLaunchKernelGGL(conv_mfma, grid, dim3(NTH), 0, stream, x, wtf, bias, mult, out);
}